// Round 2
// baseline (565.898 us; speedup 1.0000x reference)
//
#include <hip/hip_runtime.h>

#define B_ 256
#define S_ 1024
#define D_ 128
#define H_ 256

typedef short short8 __attribute__((ext_vector_type(8)));
typedef float f32x4 __attribute__((ext_vector_type(4)));

// Cross-kernel small buffers (re-written every call by prep/means0/layers).
__device__ unsigned short g_Wb0[H_ * D_];   // bf16 left-half of W0, PRE-SWIZZLED
__device__ unsigned short g_Wb1[H_ * H_];
__device__ unsigned short g_Wb2[H_ * H_];
__device__ float g_Wc0[H_ * D_];            // fp32: W_right + (W_left - bf16(W_left))
__device__ float g_Wc1[H_ * H_];
__device__ float g_Wc2[H_ * H_];
__device__ float g_mean0[B_ * D_];          // column SUMS of x
__device__ float g_colsum1[B_ * H_];        // fp32 column sums of layer outputs
__device__ float g_colsum2[B_ * H_];

__device__ __forceinline__ unsigned short f2bf(float x) {
    union { float f; unsigned u; } v; v.f = x;
    unsigned r = v.u + 0x7FFFu + ((v.u >> 16) & 1u);
    return (unsigned short)(r >> 16);
}
__device__ __forceinline__ float bf2f(unsigned short h) {
    union { float f; unsigned u; } v; v.u = ((unsigned)h) << 16;
    return v.f;
}
__device__ __forceinline__ float fast_tanh(float x) {
    float e = __builtin_amdgcn_exp2f(x * 2.885390081777927f); // 2*log2(e)
    float r = __builtin_amdgcn_rcpf(1.0f + e);
    return 1.0f - 2.0f * r;
}
__device__ __forceinline__ unsigned cvt_pk_bf16(float lo, float hi) {
    unsigned r;
    asm("v_cvt_pk_bf16_f32 %0, %1, %2" : "=v"(r) : "v"(lo), "v"(hi));
    return r;
}
__device__ __forceinline__ void gload_lds16(const unsigned short* g, unsigned short* l) {
    __builtin_amdgcn_global_load_lds(
        (const __attribute__((address_space(1))) void*)g,
        (__attribute__((address_space(3))) void*)l, 16, 0, 0);
}

// ---- prep: bf16 left-halves (pre-swizzled) + fp32 correction weights -------
__global__ __launch_bounds__(256) void prep_kernel(
    const float* __restrict__ W0, const float* __restrict__ W1,
    const float* __restrict__ W2)
{
    int i = blockIdx.x * 256 + threadIdx.x;
    const float* W; unsigned short* wb; float* wc; int kbits;
    if (i < H_ * D_) { W = W0; wb = g_Wb0; wc = g_Wc0; kbits = 7; }
    else {
        i -= H_ * D_;
        if (i < H_ * H_) { W = W1; wb = g_Wb1; wc = g_Wc1; kbits = 8; }
        else {
            i -= H_ * H_;
            if (i >= H_ * H_) return;
            W = W2; wb = g_Wb2; wc = g_Wc2; kbits = 8;
        }
    }
    const int K = 1 << kbits;
    const int n = i >> kbits, k = i & (K - 1);
    const float a = W[n * 2 * K + k];
    const float b = W[n * 2 * K + K + k];
    const unsigned short hb = f2bf(a);
    // swizzled store: 16B slot s of row n lands at slot s^(n&7)
    wb[n * K + ((((k >> 3) ^ (n & 7)) << 3) | (k & 7))] = hb;
    wc[n * K + k] = b + (a - bf2f(hb));
}

// ---- means0: one block per set, column sums of x in fp32, no atomics -------
__global__ __launch_bounds__(1024) void means0_kernel(const float* __restrict__ x)
{
    const int set = blockIdx.x, t = threadIdx.x;
    const int cg = t & 31, rg = t >> 5;               // col-group of 4, row group
    const float* xb = x + (size_t)set * S_ * D_;
    f32x4 s = (f32x4){0.f, 0.f, 0.f, 0.f};
    #pragma unroll 8
    for (int i = 0; i < 32; ++i)
        s += *(const f32x4*)(xb + (rg + i * 32) * D_ + cg * 4);
    __shared__ f32x4 red[32][32];
    red[rg][cg] = s;
    __syncthreads();
    if (t < 32) {
        f32x4 a = red[0][t];
        #pragma unroll
        for (int g = 1; g < 32; ++g) a += red[g][t];
        #pragma unroll
        for (int c = 0; c < 4; ++c) g_mean0[set * D_ + t * 4 + c] = a[c];
    }
}

// ---- layer: grid=256 (one block per set), 512 thr / 8 waves ---------------
// Wave owns 64 rows (x2 halves): A/B-fragments register-resident (128 VGPR),
// W bf16 fully LDS-resident (swizzled, async-filled). MFMA operands swapped
// (W = A operand) so the epilogue packs with cvt_pk_bf16 and stores 8B uint2.
// Column sums: per-lane f32 partials -> ds_add_f32 into padded [16][257]
// bins -> one 16-way reduce at the end (no shfl trees, no global atomics).
template <int LAYER>
__global__ __launch_bounds__(512, 2) void layer_kernel(
    const float* __restrict__ x, const float* __restrict__ bias,
    unsigned short* __restrict__ y, float* __restrict__ out)
{
    constexpr int K  = (LAYER == 0) ? D_ : H_;
    constexpr int KS = K / 32;            // 4 or 8 k-steps
    const int set = blockIdx.x;
    const int t = threadIdx.x;
    const int lane = t & 63, wave = t >> 6;
    const int l15 = lane & 15, quad = lane >> 4;

    __shared__ unsigned short W_lds[256 * K];    // 64 / 128 KB
    __shared__ float mean_lds[K];
    __shared__ float c_lds[H_];
    __shared__ float cpart[512];
    __shared__ float colsum_t[16][257];          // padded: bank = (l15+col)&31

    const unsigned short* Wb = (LAYER == 0) ? g_Wb0 : (LAYER == 1) ? g_Wb1 : g_Wb2;
    const float* Wc = (LAYER == 0) ? g_Wc0 : (LAYER == 1) ? g_Wc1 : g_Wc2;
    const float* msrc = (LAYER == 0) ? g_mean0 : (LAYER == 1) ? g_colsum1 : g_colsum2;

    // zero colsum bins, load mean, kick off async W fill (linear copy: g_Wb
    // is pre-swizzled, LDS dest is wave-uniform base + lane*16)
    #pragma unroll
    for (int i = t; i < 16 * 257; i += 512) (&colsum_t[0][0])[i] = 0.f;
    if (t < K) mean_lds[t] = msrc[set * K + t] * (1.f / S_);
    {
        constexpr int NCH = (256 * K * 2) / 1024;   // 64 or 128 chunks of 1 KiB
        #pragma unroll
        for (int c = wave; c < NCH; c += 8)
            gload_lds16(Wb + c * 512 + lane * 8, &W_lds[c * 512]);
    }
    __syncthreads();   // mean visible; implicit vmcnt drain -> W_lds ready

    // c[j] = b[j] + mean @ Wc[j].T  (fp32, Wc precomputed in prep)
    {
        const int j = t >> 1, h = t & 1;
        const float* wr = Wc + j * K + h * (K / 2);
        const float* mr = &mean_lds[h * (K / 2)];
        float acc = 0.f;
        #pragma unroll 4
        for (int k = 0; k < K / 2; k += 4) {
            f32x4 w = *(const f32x4*)(wr + k);
            f32x4 m = *(const f32x4*)(mr + k);
            #pragma unroll
            for (int c = 0; c < 4; ++c) acc += m[c] * w[c];
        }
        cpart[t] = acc;
    }
    __syncthreads();
    if (t < H_) c_lds[t] = bias[t] + cpart[2 * t] + cpart[2 * t + 1];
    __syncthreads();

    for (int half = 0; half < 2; ++half) {
        const int rowbase = half * 512 + wave * 64;   // within set

        // ---- fragments: register-resident, MFMA layout (B operand: y rows)
        short8 a[4][KS];
        if (LAYER == 0) {
            const float* xb = x + ((size_t)set * S_ + rowbase) * D_;
            #pragma unroll
            for (int mf = 0; mf < 4; ++mf)
                #pragma unroll
                for (int ks = 0; ks < KS; ++ks) {
                    const float* p = xb + (mf * 16 + l15) * D_ + ks * 32 + quad * 8;
                    f32x4 v0 = *(const f32x4*)(p);
                    f32x4 v1 = *(const f32x4*)(p + 4);
                    union { short8 s; unsigned u[4]; } sv;
                    sv.u[0] = cvt_pk_bf16(v0[0], v0[1]);
                    sv.u[1] = cvt_pk_bf16(v0[2], v0[3]);
                    sv.u[2] = cvt_pk_bf16(v1[0], v1[1]);
                    sv.u[3] = cvt_pk_bf16(v1[2], v1[3]);
                    a[mf][ks] = sv.s;
                }
        } else {
            const unsigned short* yb = y + ((size_t)set * S_ + rowbase) * H_;
            #pragma unroll
            for (int mf = 0; mf < 4; ++mf)
                #pragma unroll
                for (int ks = 0; ks < KS; ++ks)
                    a[mf][ks] = *(const short8*)(yb + (mf * 16 + l15) * H_ + ks * 32 + quad * 8);
        }

        unsigned short* ybase = y + ((size_t)set * S_ + rowbase) * H_;

        for (int nt = 0; nt < 8; ++nt) {              // 32-col n-tiles
            f32x4 acc[4][2];
            #pragma unroll
            for (int i = 0; i < 4; ++i) {
                acc[i][0] = (f32x4){0.f, 0.f, 0.f, 0.f};
                acc[i][1] = (f32x4){0.f, 0.f, 0.f, 0.f};
            }
            const int r0 = (nt * 32 + l15) * K;
            const int r1 = r0 + 16 * K;
            #pragma unroll
            for (int ks = 0; ks < KS; ++ks) {
                const int so = (((ks * 4 + quad) ^ (l15 & 7)) * 8);
                short8 w0 = *(const short8*)(&W_lds[r0 + so]);
                short8 w1 = *(const short8*)(&W_lds[r1 + so]);
                #pragma unroll
                for (int mf = 0; mf < 4; ++mf)
                    acc[mf][0] = __builtin_amdgcn_mfma_f32_16x16x32_bf16(w0, a[mf][ks], acc[mf][0], 0, 0, 0);
                #pragma unroll
                for (int mf = 0; mf < 4; ++mf)
                    acc[mf][1] = __builtin_amdgcn_mfma_f32_16x16x32_bf16(w1, a[mf][ks], acc[mf][1], 0, 0, 0);
            }
            // epilogue. D layout (swapped operands): lane holds
            // yrow = rowbase + mf*16 + l15, outcols = nt*32 + nf*16 + quad*4 + r
            #pragma unroll
            for (int nf = 0; nf < 2; ++nf) {
                const int colbase = nt * 32 + nf * 16 + quad * 4;
                const f32x4 cv = *(const f32x4*)(&c_lds[colbase]);
                f32x4 cs = (f32x4){0.f, 0.f, 0.f, 0.f};
                #pragma unroll
                for (int mf = 0; mf < 4; ++mf) {
                    f32x4 th;
                    #pragma unroll
                    for (int r = 0; r < 4; ++r)
                        th[r] = fast_tanh(acc[mf][nf][r] + cv[r]);
                    cs += th;
                    if (LAYER < 2) {
                        uint2 pv;
                        pv.x = cvt_pk_bf16(th[0], th[1]);
                        pv.y = cvt_pk_bf16(th[2], th[3]);
                        *(uint2*)(&ybase[(mf * 16 + l15) * H_ + colbase]) = pv;
                    }
                }
                // fire-and-forget fp32 LDS atomics, lane-distinct addresses
                atomicAdd(&colsum_t[l15][colbase + 0], cs[0]);
                atomicAdd(&colsum_t[l15][colbase + 1], cs[1]);
                atomicAdd(&colsum_t[l15][colbase + 2], cs[2]);
                atomicAdd(&colsum_t[l15][colbase + 3], cs[3]);
            }
        }
    }
    __syncthreads();
    if (t < H_) {
        float v = 0.f;
        #pragma unroll
        for (int g = 0; g < 16; ++g) v += colsum_t[g][t];
        if (LAYER == 2)      out[set * H_ + t] = v * (1.f / S_);
        else if (LAYER == 1) g_colsum2[set * H_ + t] = v;
        else                 g_colsum1[set * H_ + t] = v;
    }
}

extern "C" void kernel_launch(void* const* d_in, const int* in_sizes, int n_in,
                              void* d_out, int out_size, void* d_ws, size_t ws_size,
                              hipStream_t stream) {
    (void)in_sizes; (void)n_in; (void)out_size; (void)ws_size;
    const float* x  = (const float*)d_in[0];
    const float* W0 = (const float*)d_in[1];
    const float* b0 = (const float*)d_in[2];
    const float* W1 = (const float*)d_in[3];
    const float* b1 = (const float*)d_in[4];
    const float* W2 = (const float*)d_in[5];
    const float* b2 = (const float*)d_in[6];
    float* out = (float*)d_out;
    unsigned short* ws = (unsigned short*)d_ws;   // y: [256][1024][256] bf16 = 128 MiB

    prep_kernel<<<dim3(640), dim3(256), 0, stream>>>(W0, W1, W2);
    means0_kernel<<<dim3(256), dim3(1024), 0, stream>>>(x);
    layer_kernel<0><<<dim3(256), dim3(512), 0, stream>>>(x, b0, ws, out);
    layer_kernel<1><<<dim3(256), dim3(512), 0, stream>>>(x, b1, ws, out);
    layer_kernel<2><<<dim3(256), dim3(512), 0, stream>>>(x, b2, ws, out);
}

// Round 3
// 409.075 us; speedup vs baseline: 1.3834x; 1.3834x over previous
//
#include <hip/hip_runtime.h>

#define B_ 256
#define S_ 1024
#define D_ 128
#define H_ 256

typedef short short8 __attribute__((ext_vector_type(8)));
typedef float f32x4 __attribute__((ext_vector_type(4)));

// Cross-kernel small buffers (re-written every call by prep/means0/layers).
__device__ unsigned short g_Wb0[H_ * D_];   // bf16 left-half of W0, PRE-SWIZZLED
__device__ unsigned short g_Wb1[H_ * H_];
__device__ unsigned short g_Wb2[H_ * H_];
__device__ float g_Wc0[H_ * D_];            // fp32: W_right + (W_left - bf16(W_left))
__device__ float g_Wc1[H_ * H_];
__device__ float g_Wc2[H_ * H_];
__device__ float g_mean0[B_ * D_];          // column SUMS of x
__device__ float g_colsum1[B_ * H_];        // fp32 column sums of layer outputs
__device__ float g_colsum2[B_ * H_];

__device__ __forceinline__ unsigned short f2bf(float x) {
    union { float f; unsigned u; } v; v.f = x;
    unsigned r = v.u + 0x7FFFu + ((v.u >> 16) & 1u);
    return (unsigned short)(r >> 16);
}
__device__ __forceinline__ float bf2f(unsigned short h) {
    union { float f; unsigned u; } v; v.u = ((unsigned)h) << 16;
    return v.f;
}
__device__ __forceinline__ float fast_tanh(float x) {
    float e = __builtin_amdgcn_exp2f(x * 2.885390081777927f); // 2*log2(e)
    float r = __builtin_amdgcn_rcpf(1.0f + e);
    return 1.0f - 2.0f * r;
}
__device__ __forceinline__ unsigned cvt_pk_bf16(float lo, float hi) {
    unsigned r;
    asm("v_cvt_pk_bf16_f32 %0, %1, %2" : "=v"(r) : "v"(lo), "v"(hi));
    return r;
}
__device__ __forceinline__ void gload_lds16(const unsigned short* g, unsigned short* l) {
    __builtin_amdgcn_global_load_lds(
        (const __attribute__((address_space(1))) void*)g,
        (__attribute__((address_space(3))) void*)l, 16, 0, 0);
}
// Sum across each 16-lane row (DPP row_shr chain, pure VALU — no LDS pipe).
// Lane (l&15)==15 of each row ends up holding the 16-lane total.
__device__ __forceinline__ float row16_reduce_add(float v) {
    int s;
    s = __builtin_amdgcn_update_dpp(0, __builtin_bit_cast(int, v), 0x111, 0xF, 0xF, true);
    v += __builtin_bit_cast(float, s);
    s = __builtin_amdgcn_update_dpp(0, __builtin_bit_cast(int, v), 0x112, 0xF, 0xF, true);
    v += __builtin_bit_cast(float, s);
    s = __builtin_amdgcn_update_dpp(0, __builtin_bit_cast(int, v), 0x114, 0xF, 0xF, true);
    v += __builtin_bit_cast(float, s);
    s = __builtin_amdgcn_update_dpp(0, __builtin_bit_cast(int, v), 0x118, 0xF, 0xF, true);
    v += __builtin_bit_cast(float, s);
    return v;
}

// ---- prep: bf16 left-halves (pre-swizzled) + fp32 correction weights -------
__global__ __launch_bounds__(256) void prep_kernel(
    const float* __restrict__ W0, const float* __restrict__ W1,
    const float* __restrict__ W2)
{
    int i = blockIdx.x * 256 + threadIdx.x;
    const float* W; unsigned short* wb; float* wc; int kbits;
    if (i < H_ * D_) { W = W0; wb = g_Wb0; wc = g_Wc0; kbits = 7; }
    else {
        i -= H_ * D_;
        if (i < H_ * H_) { W = W1; wb = g_Wb1; wc = g_Wc1; kbits = 8; }
        else {
            i -= H_ * H_;
            if (i >= H_ * H_) return;
            W = W2; wb = g_Wb2; wc = g_Wc2; kbits = 8;
        }
    }
    const int K = 1 << kbits;
    const int n = i >> kbits, k = i & (K - 1);
    const float a = W[n * 2 * K + k];
    const float b = W[n * 2 * K + K + k];
    const unsigned short hb = f2bf(a);
    // swizzled store: 16B slot s of row n lands at slot s^(n&7)
    wb[n * K + ((((k >> 3) ^ (n & 7)) << 3) | (k & 7))] = hb;
    wc[n * K + k] = b + (a - bf2f(hb));
}

// ---- means0: one block per set, column sums of x in fp32, no atomics -------
__global__ __launch_bounds__(1024) void means0_kernel(const float* __restrict__ x)
{
    const int set = blockIdx.x, t = threadIdx.x;
    const int cg = t & 31, rg = t >> 5;               // col-group of 4, row group
    const float* xb = x + (size_t)set * S_ * D_;
    f32x4 s = (f32x4){0.f, 0.f, 0.f, 0.f};
    #pragma unroll 8
    for (int i = 0; i < 32; ++i)
        s += *(const f32x4*)(xb + (rg + i * 32) * D_ + cg * 4);
    __shared__ f32x4 red[32][32];
    red[rg][cg] = s;
    __syncthreads();
    if (t < 32) {
        f32x4 a = red[0][t];
        #pragma unroll
        for (int g = 1; g < 32; ++g) a += red[g][t];
        #pragma unroll
        for (int c = 0; c < 4; ++c) g_mean0[set * D_ + t * 4 + c] = a[c];
    }
}

// ---- layer: grid=256 (one block per set), 512 thr / 8 waves ---------------
// Wave owns 64 rows (x2 halves): fragments register-resident, W bf16 fully
// LDS-resident (swizzled, async-filled). MFMA operands swapped (W = A) so the
// epilogue packs with cvt_pk_bf16 and stores 8B uint2. Column sums stay OFF
// the LDS pipe: DPP row-reduce (VALU) -> lane-15 ds_write_b128 into per-
// (half,wave) slots, each column written exactly once -> 16-way final reduce.
template <int LAYER>
__global__ __launch_bounds__(512, 2) void layer_kernel(
    const float* __restrict__ x, const float* __restrict__ bias,
    unsigned short* __restrict__ y, float* __restrict__ out)
{
    constexpr int K  = (LAYER == 0) ? D_ : H_;
    constexpr int KS = K / 32;            // 4 or 8 k-steps
    const int set = blockIdx.x;
    const int t = threadIdx.x;
    const int lane = t & 63, wave = t >> 6;
    const int l15 = lane & 15, quad = lane >> 4;

    __shared__ unsigned short W_lds[256 * K];    // 64 / 128 KB
    __shared__ float mean_lds[K];
    __shared__ float c_lds[H_];
    __shared__ float cpart[512];
    __shared__ float colsum_w[2][8][H_];         // [half][wave][col], 16 KB

    const unsigned short* Wb = (LAYER == 0) ? g_Wb0 : (LAYER == 1) ? g_Wb1 : g_Wb2;
    const float* Wc = (LAYER == 0) ? g_Wc0 : (LAYER == 1) ? g_Wc1 : g_Wc2;
    const float* msrc = (LAYER == 0) ? g_mean0 : (LAYER == 1) ? g_colsum1 : g_colsum2;

    // load mean, kick off async W fill (linear copy: g_Wb is pre-swizzled,
    // LDS dest is wave-uniform base + lane*16)
    if (t < K) mean_lds[t] = msrc[set * K + t] * (1.f / S_);
    {
        constexpr int NCH = (256 * K * 2) / 1024;   // 64 or 128 chunks of 1 KiB
        #pragma unroll
        for (int c = wave; c < NCH; c += 8)
            gload_lds16(Wb + c * 512 + lane * 8, &W_lds[c * 512]);
    }
    __syncthreads();   // mean visible; implicit vmcnt drain -> W_lds ready

    // c[j] = b[j] + mean @ Wc[j].T  (fp32, Wc precomputed in prep)
    {
        const int j = t >> 1, h = t & 1;
        const float* wr = Wc + j * K + h * (K / 2);
        const float* mr = &mean_lds[h * (K / 2)];
        float acc = 0.f;
        #pragma unroll 4
        for (int k = 0; k < K / 2; k += 4) {
            f32x4 w = *(const f32x4*)(wr + k);
            f32x4 m = *(const f32x4*)(mr + k);
            #pragma unroll
            for (int c = 0; c < 4; ++c) acc += m[c] * w[c];
        }
        cpart[t] = acc;
    }
    __syncthreads();
    if (t < H_) c_lds[t] = bias[t] + cpart[2 * t] + cpart[2 * t + 1];
    __syncthreads();

    for (int half = 0; half < 2; ++half) {
        const int rowbase = half * 512 + wave * 64;   // within set

        // ---- fragments: register-resident, MFMA layout (B operand: y rows)
        short8 a[4][KS];
        if (LAYER == 0) {
            const float* xb = x + ((size_t)set * S_ + rowbase) * D_;
            #pragma unroll
            for (int mf = 0; mf < 4; ++mf)
                #pragma unroll
                for (int ks = 0; ks < KS; ++ks) {
                    const float* p = xb + (mf * 16 + l15) * D_ + ks * 32 + quad * 8;
                    f32x4 v0 = *(const f32x4*)(p);
                    f32x4 v1 = *(const f32x4*)(p + 4);
                    union { short8 s; unsigned u[4]; } sv;
                    sv.u[0] = cvt_pk_bf16(v0[0], v0[1]);
                    sv.u[1] = cvt_pk_bf16(v0[2], v0[3]);
                    sv.u[2] = cvt_pk_bf16(v1[0], v1[1]);
                    sv.u[3] = cvt_pk_bf16(v1[2], v1[3]);
                    a[mf][ks] = sv.s;
                }
        } else {
            const unsigned short* yb = y + ((size_t)set * S_ + rowbase) * H_;
            #pragma unroll
            for (int mf = 0; mf < 4; ++mf)
                #pragma unroll
                for (int ks = 0; ks < KS; ++ks)
                    a[mf][ks] = *(const short8*)(yb + (mf * 16 + l15) * H_ + ks * 32 + quad * 8);
        }

        unsigned short* ybase = y + ((size_t)set * S_ + rowbase) * H_;

        for (int nt = 0; nt < 8; ++nt) {              // 32-col n-tiles
            f32x4 acc[4][2];
            #pragma unroll
            for (int i = 0; i < 4; ++i) {
                acc[i][0] = (f32x4){0.f, 0.f, 0.f, 0.f};
                acc[i][1] = (f32x4){0.f, 0.f, 0.f, 0.f};
            }
            const int r0 = (nt * 32 + l15) * K;
            const int r1 = r0 + 16 * K;
            #pragma unroll
            for (int ks = 0; ks < KS; ++ks) {
                const int so = (((ks * 4 + quad) ^ (l15 & 7)) * 8);
                short8 w0 = *(const short8*)(&W_lds[r0 + so]);
                short8 w1 = *(const short8*)(&W_lds[r1 + so]);
                #pragma unroll
                for (int mf = 0; mf < 4; ++mf)
                    acc[mf][0] = __builtin_amdgcn_mfma_f32_16x16x32_bf16(w0, a[mf][ks], acc[mf][0], 0, 0, 0);
                #pragma unroll
                for (int mf = 0; mf < 4; ++mf)
                    acc[mf][1] = __builtin_amdgcn_mfma_f32_16x16x32_bf16(w1, a[mf][ks], acc[mf][1], 0, 0, 0);
            }
            // epilogue. D layout (swapped operands): lane holds
            // yrow = rowbase + mf*16 + l15, outcols = nt*32 + nf*16 + quad*4 + r
            #pragma unroll
            for (int nf = 0; nf < 2; ++nf) {
                const int colbase = nt * 32 + nf * 16 + quad * 4;
                const f32x4 cv = *(const f32x4*)(&c_lds[colbase]);
                f32x4 cs = (f32x4){0.f, 0.f, 0.f, 0.f};
                #pragma unroll
                for (int mf = 0; mf < 4; ++mf) {
                    f32x4 th;
                    #pragma unroll
                    for (int r = 0; r < 4; ++r)
                        th[r] = fast_tanh(acc[mf][nf][r] + cv[r]);
                    cs += th;
                    if (LAYER < 2) {
                        uint2 pv;
                        pv.x = cvt_pk_bf16(th[0], th[1]);
                        pv.y = cvt_pk_bf16(th[2], th[3]);
                        *(uint2*)(&ybase[(mf * 16 + l15) * H_ + colbase]) = pv;
                    }
                }
                // column sum over the 16 row-lanes: DPP chain (VALU only),
                // then lane 15 of each quad stores its 4 cols once.
                #pragma unroll
                for (int r = 0; r < 4; ++r) cs[r] = row16_reduce_add(cs[r]);
                if (l15 == 15)
                    *(f32x4*)(&colsum_w[half][wave][colbase]) = cs;
            }
        }
    }
    __syncthreads();
    if (t < H_) {
        float v = 0.f;
        #pragma unroll
        for (int i = 0; i < 16; ++i) v += colsum_w[i >> 3][i & 7][t];
        if (LAYER == 2)      out[set * H_ + t] = v * (1.f / S_);
        else if (LAYER == 1) g_colsum2[set * H_ + t] = v;
        else                 g_colsum1[set * H_ + t] = v;
    }
}

extern "C" void kernel_launch(void* const* d_in, const int* in_sizes, int n_in,
                              void* d_out, int out_size, void* d_ws, size_t ws_size,
                              hipStream_t stream) {
    (void)in_sizes; (void)n_in; (void)out_size; (void)ws_size;
    const float* x  = (const float*)d_in[0];
    const float* W0 = (const float*)d_in[1];
    const float* b0 = (const float*)d_in[2];
    const float* W1 = (const float*)d_in[3];
    const float* b1 = (const float*)d_in[4];
    const float* W2 = (const float*)d_in[5];
    const float* b2 = (const float*)d_in[6];
    float* out = (float*)d_out;
    unsigned short* ws = (unsigned short*)d_ws;   // y: [256][1024][256] bf16 = 128 MiB

    prep_kernel<<<dim3(640), dim3(256), 0, stream>>>(W0, W1, W2);
    means0_kernel<<<dim3(256), dim3(1024), 0, stream>>>(x);
    layer_kernel<0><<<dim3(256), dim3(512), 0, stream>>>(x, b0, ws, out);
    layer_kernel<1><<<dim3(256), dim3(512), 0, stream>>>(x, b1, ws, out);
    layer_kernel<2><<<dim3(256), dim3(512), 0, stream>>>(x, b2, ws, out);
}

// Round 4
// 384.554 us; speedup vs baseline: 1.4716x; 1.0638x over previous
//
#include <hip/hip_runtime.h>

#define B_ 256
#define S_ 1024
#define D_ 128
#define H_ 256

typedef short short8 __attribute__((ext_vector_type(8)));
typedef float f32x4 __attribute__((ext_vector_type(4)));

// Cross-kernel buffers (re-written every call).
__device__ unsigned short g_Wb0[H_ * D_];   // bf16 left-halves, FRAG-ORDERED
__device__ unsigned short g_Wb1[H_ * H_];
__device__ unsigned short g_Wb2[H_ * H_];
__device__ float g_Wc0[H_ * D_];            // fp32: W_right + (W_left - bf16(W_left))
__device__ float g_Wc1[H_ * H_];
__device__ float g_Wc2[H_ * H_];
__device__ float g_mean0[B_ * D_];          // column SUMS of x
__device__ float g_colsum1[B_ * H_];        // column sums of layer outputs
__device__ float g_colsum2[B_ * H_];
__device__ float g_c0[B_ * H_];             // per-set bias+mean vectors
__device__ float g_c1[B_ * H_];
__device__ float g_c2[B_ * H_];
__device__ unsigned short g_xb[(size_t)B_ * S_ * D_];  // bf16 x, row-swizzled (64 MiB)

__device__ __forceinline__ unsigned short f2bf(float x) {
    union { float f; unsigned u; } v; v.f = x;
    unsigned r = v.u + 0x7FFFu + ((v.u >> 16) & 1u);
    return (unsigned short)(r >> 16);
}
__device__ __forceinline__ float bf2f(unsigned short h) {
    union { float f; unsigned u; } v; v.u = ((unsigned)h) << 16;
    return v.f;
}
__device__ __forceinline__ float fast_tanh(float x) {
    float e = __builtin_amdgcn_exp2f(x * 2.885390081777927f); // 2*log2(e)
    float r = __builtin_amdgcn_rcpf(1.0f + e);
    return 1.0f - 2.0f * r;
}
__device__ __forceinline__ unsigned cvt_pk_bf16(float lo, float hi) {
    unsigned r;
    asm("v_cvt_pk_bf16_f32 %0, %1, %2" : "=v"(r) : "v"(lo), "v"(hi));
    return r;
}
__device__ __forceinline__ void gload_lds16(const unsigned short* g, unsigned short* l) {
    __builtin_amdgcn_global_load_lds(
        (const __attribute__((address_space(1))) void*)g,
        (__attribute__((address_space(3))) void*)l, 16, 0, 0);
}
// Sum across each 16-lane group (DPP row_shr chain, pure VALU).
// Lane (l&15)==15 of each group ends up holding the 16-lane total.
__device__ __forceinline__ float row16_reduce_add(float v) {
    int s;
    s = __builtin_amdgcn_update_dpp(0, __builtin_bit_cast(int, v), 0x111, 0xF, 0xF, true);
    v += __builtin_bit_cast(float, s);
    s = __builtin_amdgcn_update_dpp(0, __builtin_bit_cast(int, v), 0x112, 0xF, 0xF, true);
    v += __builtin_bit_cast(float, s);
    s = __builtin_amdgcn_update_dpp(0, __builtin_bit_cast(int, v), 0x114, 0xF, 0xF, true);
    v += __builtin_bit_cast(float, s);
    s = __builtin_amdgcn_update_dpp(0, __builtin_bit_cast(int, v), 0x118, 0xF, 0xF, true);
    v += __builtin_bit_cast(float, s);
    return v;
}

// ---- prep: W left-halves -> bf16 frag-ordered; Wc fp32 correction ----------
__global__ __launch_bounds__(256) void prep_kernel(
    const float* __restrict__ W0, const float* __restrict__ W1,
    const float* __restrict__ W2)
{
    int i = blockIdx.x * 256 + threadIdx.x;
    const float* W; unsigned short* wb; float* wc; int kbits;
    if (i < H_ * D_) { W = W0; wb = g_Wb0; wc = g_Wc0; kbits = 7; }
    else {
        i -= H_ * D_;
        if (i < H_ * H_) { W = W1; wb = g_Wb1; wc = g_Wc1; kbits = 8; }
        else {
            i -= H_ * H_;
            if (i >= H_ * H_) return;
            W = W2; wb = g_Wb2; wc = g_Wc2; kbits = 8;
        }
    }
    const int K = 1 << kbits, KS = K >> 5;
    const int n = i >> kbits, k = i & (K - 1);
    const float a = W[n * 2 * K + k];
    const float b = W[n * 2 * K + K + k];
    const unsigned short hb = f2bf(a);
    // frag order: [w][cf][ks][lane][e] with lane = quad*16 + l15
    const int w = n >> 5, cf = (n >> 4) & 1, l15 = n & 15;
    const int ks = k >> 5, quad = (k >> 3) & 3, e = k & 7;
    wb[(((w * 2 + cf) * KS + ks) * 64 + quad * 16 + l15) * 8 + e] = hb;
    wc[n * K + k] = b + (a - bf2f(hb));
}

// ---- means0: column sums of x + bf16 swizzled copy of x --------------------
__global__ __launch_bounds__(1024) void means0_kernel(const float* __restrict__ x)
{
    const int set = blockIdx.x, t = threadIdx.x;
    const int cg = t & 31, rg = t >> 5;               // col-group of 4, row group
    const float* xs = x + (size_t)set * S_ * D_;
    unsigned short* xd = g_xb + (size_t)set * S_ * D_;
    const int slot = cg >> 1, halfsel = (cg & 1) * 4;
    f32x4 s = (f32x4){0.f, 0.f, 0.f, 0.f};
    #pragma unroll 8
    for (int i = 0; i < 32; ++i) {
        const int row = rg + i * 32;
        f32x4 v = *(const f32x4*)(xs + row * D_ + cg * 4);
        s += v;
        uint2 pv;
        pv.x = cvt_pk_bf16(v[0], v[1]);
        pv.y = cvt_pk_bf16(v[2], v[3]);
        *(uint2*)(&xd[row * D_ + ((slot ^ (row & 7)) * 8) + halfsel]) = pv;
    }
    __shared__ f32x4 red[32][32];
    red[rg][cg] = s;
    __syncthreads();
    if (t < 32) {
        f32x4 a = red[0][t];
        #pragma unroll
        for (int g = 1; g < 32; ++g) a += red[g][t];
        #pragma unroll
        for (int c = 0; c < 4; ++c) g_mean0[set * D_ + t * 4 + c] = a[c];
    }
}

// ---- c-vector kernel: c[set][j] = bias[j] + mean[set] . Wc[j] --------------
// grid 64: block handles 4 sets x all 256 cols; Wc read once per block.
template <int L>
__global__ __launch_bounds__(256) void c_kernel(const float* __restrict__ bias)
{
    constexpr int K = (L == 0) ? D_ : H_;
    constexpr int KB = (L == 0) ? 7 : 8;
    const int j = threadIdx.x, sg = blockIdx.x * 4;
    const float* Wc = (L == 0) ? g_Wc0 : (L == 1) ? g_Wc1 : g_Wc2;
    const float* ms = (L == 0) ? g_mean0 : (L == 1) ? g_colsum1 : g_colsum2;
    float* dst = (L == 0) ? g_c0 : (L == 1) ? g_c1 : g_c2;
    __shared__ float m_lds[4][H_];
    for (int i = j; i < 4 * K; i += 256)
        m_lds[i >> KB][i & (K - 1)] = ms[(sg + (i >> KB)) * K + (i & (K - 1))] * (1.f / S_);
    __syncthreads();
    const float* wr = Wc + j * K;
    float a0 = 0.f, a1 = 0.f, a2 = 0.f, a3 = 0.f;
    #pragma unroll 4
    for (int k = 0; k < K; k += 4) {
        f32x4 w = *(const f32x4*)(wr + k);
        #pragma unroll
        for (int c = 0; c < 4; ++c) {
            a0 += m_lds[0][k + c] * w[c];
            a1 += m_lds[1][k + c] * w[c];
            a2 += m_lds[2][k + c] * w[c];
            a3 += m_lds[3][k + c] * w[c];
        }
    }
    const float bb = bias[j];
    dst[(sg + 0) * H_ + j] = bb + a0;
    dst[(sg + 1) * H_ + j] = bb + a1;
    dst[(sg + 2) * H_ + j] = bb + a2;
    dst[(sg + 3) * H_ + j] = bb + a3;
}

// ---- layer: grid=256 (one block per set), 512 thr / 8 waves ---------------
// W-fragments in registers (wave owns 32 output cols); y/x streamed in
// 64-row tiles through LDS via async global_load_lds, double-buffered
// (2-phase: issue stage(t+1), compute t, one barrier per tile). Global y/xb
// are stored row-swizzled (slot ^= row&7) so the linear LDS copy yields
// bank-spread ds_read_b128 fragment reads. Colsums accumulate in registers
// (wave exclusively owns its cols across all rows) -> DPP reduce at end.
template <int LAYER>
__global__ __launch_bounds__(512, 2) void layer_kernel(
    unsigned short* ybuf, float* __restrict__ out)
{
    constexpr int K  = (LAYER == 0) ? D_ : H_;
    constexpr int KS = K / 32;
    constexpr int NCH = (64 * K / 8) / 512;   // 16B chunks per thread per tile
    constexpr int NT = S_ / 64;               // 16 tiles
    const int set = blockIdx.x;
    const int t = threadIdx.x;
    const int lane = t & 63, wave = t >> 6;
    const int l15 = lane & 15, quad = lane >> 4;

    __shared__ __align__(16) unsigned short y_lds[2][64 * K];

    const unsigned short* Wb = (LAYER == 0) ? g_Wb0 : (LAYER == 1) ? g_Wb1 : g_Wb2;
    const float* cvec = (LAYER == 0) ? g_c0 : (LAYER == 1) ? g_c1 : g_c2;
    const unsigned short* ysrc = (LAYER == 0) ? g_xb + (size_t)set * S_ * D_
                                              : ybuf + (size_t)set * S_ * H_;
    unsigned short* ydst = ybuf + (size_t)set * S_ * H_;

    // W fragments: frag-ordered global layout -> perfectly coalesced b128 loads
    short8 wf[2][KS];
    {
        const unsigned short* wb = Wb + (wave * 2 * KS * 64 + lane) * 8;
        #pragma unroll
        for (int cf = 0; cf < 2; ++cf)
            #pragma unroll
            for (int ks = 0; ks < KS; ++ks)
                wf[cf][ks] = *(const short8*)(wb + (cf * KS + ks) * 512);
    }
    const float* cv = cvec + set * H_ + wave * 32 + quad * 4;
    f32x4 creg0 = *(const f32x4*)(cv);
    f32x4 creg1 = *(const f32x4*)(cv + 16);

    // stage tile 0
    #pragma unroll
    for (int c = 0; c < NCH; ++c)
        gload_lds16(ysrc + (c * 512 + t) * 8, &y_lds[0][(c * 512 + t) * 8]);

    f32x4 cs0 = (f32x4){0.f, 0.f, 0.f, 0.f};
    f32x4 cs1 = (f32x4){0.f, 0.f, 0.f, 0.f};
    __syncthreads();

    for (int tt = 0; tt < NT; ++tt) {
        const int buf = tt & 1;
        if (tt + 1 < NT) {
            const unsigned short* src = ysrc + (tt + 1) * 64 * K;
            #pragma unroll
            for (int c = 0; c < NCH; ++c)
                gload_lds16(src + (c * 512 + t) * 8, &y_lds[buf ^ 1][(c * 512 + t) * 8]);
        }
        const unsigned short* yl = y_lds[buf];
        #pragma unroll
        for (int rf = 0; rf < 4; ++rf) {
            short8 bfr[KS];
            #pragma unroll
            for (int ks = 0; ks < KS; ++ks)
                bfr[ks] = *(const short8*)(
                    &yl[(rf * 16 + l15) * K + (((ks * 4 + quad) ^ (l15 & 7)) * 8)]);
            f32x4 ac0 = (f32x4){0.f, 0.f, 0.f, 0.f};
            f32x4 ac1 = (f32x4){0.f, 0.f, 0.f, 0.f};
            #pragma unroll
            for (int ks = 0; ks < KS; ++ks) {
                ac0 = __builtin_amdgcn_mfma_f32_16x16x32_bf16(wf[0][ks], bfr[ks], ac0, 0, 0, 0);
                ac1 = __builtin_amdgcn_mfma_f32_16x16x32_bf16(wf[1][ks], bfr[ks], ac1, 0, 0, 0);
            }
            // D layout: lane -> y-row = rf*16+l15 (B op), cols = wave*32+cf*16+quad*4+r (A op)
            const int row = tt * 64 + rf * 16 + l15;
            f32x4 th0, th1;
            #pragma unroll
            for (int r = 0; r < 4; ++r) th0[r] = fast_tanh(ac0[r] + creg0[r]);
            #pragma unroll
            for (int r = 0; r < 4; ++r) th1[r] = fast_tanh(ac1[r] + creg1[r]);
            cs0 += th0; cs1 += th1;
            if (LAYER < 2) {
                const int slot0 = wave * 4 + (quad >> 1);     // cf=0
                const int slot1 = slot0 + 2;                  // cf=1
                uint2 p0, p1;
                p0.x = cvt_pk_bf16(th0[0], th0[1]); p0.y = cvt_pk_bf16(th0[2], th0[3]);
                p1.x = cvt_pk_bf16(th1[0], th1[1]); p1.y = cvt_pk_bf16(th1[2], th1[3]);
                unsigned short* yr = ydst + row * H_ + (quad & 1) * 4;
                *(uint2*)(&yr[(slot0 ^ (row & 7)) * 8]) = p0;
                *(uint2*)(&yr[(slot1 ^ (row & 7)) * 8]) = p1;
            }
        }
        __syncthreads();   // drains vmcnt (stage + y-stores) and lgkm; buf swap safe
    }

    // colsum finalize: 16-lane DPP reduce; lane l15==15 stores its 4 cols per cf
    #pragma unroll
    for (int r = 0; r < 4; ++r) {
        cs0[r] = row16_reduce_add(cs0[r]);
        cs1[r] = row16_reduce_add(cs1[r]);
    }
    if (l15 == 15) {
        const int col = wave * 32 + quad * 4;
        if (LAYER == 2) {
            f32x4 o0, o1;
            #pragma unroll
            for (int r = 0; r < 4; ++r) { o0[r] = cs0[r] * (1.f / S_); o1[r] = cs1[r] * (1.f / S_); }
            *(f32x4*)(&out[set * H_ + col]) = o0;
            *(f32x4*)(&out[set * H_ + col + 16]) = o1;
        } else if (LAYER == 1) {
            *(f32x4*)(&g_colsum2[set * H_ + col]) = cs0;
            *(f32x4*)(&g_colsum2[set * H_ + col + 16]) = cs1;
        } else {
            *(f32x4*)(&g_colsum1[set * H_ + col]) = cs0;
            *(f32x4*)(&g_colsum1[set * H_ + col + 16]) = cs1;
        }
    }
}

extern "C" void kernel_launch(void* const* d_in, const int* in_sizes, int n_in,
                              void* d_out, int out_size, void* d_ws, size_t ws_size,
                              hipStream_t stream) {
    (void)in_sizes; (void)n_in; (void)out_size; (void)ws_size;
    const float* x  = (const float*)d_in[0];
    const float* W0 = (const float*)d_in[1];
    const float* b0 = (const float*)d_in[2];
    const float* W1 = (const float*)d_in[3];
    const float* b1 = (const float*)d_in[4];
    const float* W2 = (const float*)d_in[5];
    const float* b2 = (const float*)d_in[6];
    float* out = (float*)d_out;
    unsigned short* ws = (unsigned short*)d_ws;   // y: [256][1024][256] bf16 = 128 MiB

    prep_kernel<<<dim3(640), dim3(256), 0, stream>>>(W0, W1, W2);
    means0_kernel<<<dim3(256), dim3(1024), 0, stream>>>(x);
    c_kernel<0><<<dim3(64), dim3(256), 0, stream>>>(b0);
    layer_kernel<0><<<dim3(256), dim3(512), 0, stream>>>(ws, out);
    c_kernel<1><<<dim3(64), dim3(256), 0, stream>>>(b1);
    layer_kernel<1><<<dim3(256), dim3(512), 0, stream>>>(ws, out);
    c_kernel<2><<<dim3(64), dim3(256), 0, stream>>>(b2);
    layer_kernel<2><<<dim3(256), dim3(512), 0, stream>>>(ws, out);
}